// Round 15
// baseline (182.059 us; speedup 1.0000x reference)
//
#include <hip/hip_runtime.h>
#include <stdint.h>

typedef unsigned short u16;
typedef unsigned int u32;

constexpr int C = 1024;
constexpr int E = 8;
constexpr int D = 1024;
constexpr int BM = 128, BN = 128, BK = 32;   // r11 GEMM structure (best measured)
constexpr int WLS = 1032;                    // wl row stride (16B-aligned, bank-staggered)

typedef short s16x8 __attribute__((ext_vector_type(8)));
typedef float f32x4 __attribute__((ext_vector_type(4)));

__device__ __forceinline__ u16 f2bf(float f) {
  union { float f; u32 u; } v; v.f = f;
  return (u16)((v.u + 0x7FFFu + ((v.u >> 16) & 1u)) >> 16);
}
__device__ __forceinline__ float bf2f(u32 u) {
  union { u32 u; float f; } v; v.u = u << 16; return v.f;
}

typedef __attribute__((address_space(1))) const u32 gu32;
typedef __attribute__((address_space(3))) u32 lu32;
__device__ __forceinline__ void gl_lds16(const void* g, void* l) {
  __builtin_amdgcn_global_load_lds((gu32*)g, (lu32*)l, 16, 0, 0);
}
template <int N>
__device__ __forceinline__ void waitvm() {
  asm volatile("s_waitcnt vmcnt(%0)" :: "i"(N) : "memory");
  __builtin_amdgcn_sched_barrier(0);
}
__device__ __forceinline__ void bar() {
  __builtin_amdgcn_s_barrier();
  __builtin_amdgcn_sched_barrier(0);
}

// ---------------- fused prep: router (RB blocks) + w1t/w2t transpose (4096 blocks) ----------------
// One LDS pool (34.2 KB) carved per branch -> 4 blocks/CU; wl padded to kill bank conflicts.
__global__ void __launch_bounds__(256) k_prep(const float* __restrict__ x,
                                              const float* __restrict__ wr,
                                              const float* __restrict__ w1,
                                              const float* __restrict__ w2,
                                              u16* __restrict__ xb,
                                              u16* __restrict__ w1t,
                                              u16* __restrict__ w2t,
                                              int* __restrict__ tok_e,
                                              float* __restrict__ tok_p,
                                              int* __restrict__ counts,
                                              int RB) {
  __shared__ __align__(16) float pool[8 * WLS + 32 * 9 + 8];   // 34.2 KB
  int b = blockIdx.x;
  int t = threadIdx.x;
  if (b >= RB) {
    // ---- weight transpose-convert block: w[e][k][n] f32 -> wt[e][n][k] bf16 ----
    float (*tile)[65] = (float (*)[65])pool;                    // 16.6 KB of the pool
    int b2 = b - RB;
    int which = b2 >> 11;            // 0: w1, 1: w2
    int rem = b2 & 2047;
    int e = rem >> 8, kt = (rem >> 4) & 15, nt = rem & 15;
    const float* src = (which ? w2 : w1) + (size_t)e * C * D;
    u16* dst = (which ? w2t : w1t) + (size_t)e * C * D;
#pragma unroll
    for (int i = 0; i < 4; ++i) {
      int lin = i * 256 + t;
      int r = lin >> 4, c4 = lin & 15;
      f32x4 v = *(const f32x4*)(src + (size_t)(kt * 64 + r) * 1024 + nt * 64 + c4 * 4);
      tile[r][c4 * 4 + 0] = v[0]; tile[r][c4 * 4 + 1] = v[1];
      tile[r][c4 * 4 + 2] = v[2]; tile[r][c4 * 4 + 3] = v[3];
    }
    __syncthreads();
#pragma unroll
    for (int i = 0; i < 2; ++i) {
      int lin = i * 256 + t;
      int nr = lin >> 3, k8 = lin & 7;
      u32 o[4];
#pragma unroll
      for (int j = 0; j < 4; ++j)
        o[j] = (u32)f2bf(tile[k8 * 8 + 2 * j][nr]) |
               ((u32)f2bf(tile[k8 * 8 + 2 * j + 1][nr]) << 16);
      *(uint4*)(dst + (size_t)(nt * 64 + nr) * 1024 + kt * 64 + k8 * 8) = *(const uint4*)o;
    }
    return;
  }
  // ---- router block: 32 tokens -> logits (f32), top-2, softmax, counts, x->bf16 ----
  float* wl = pool;                               // [8][WLS]; row base bank = 8e mod 32
  float (*lg)[9] = (float (*)[9])(pool + 8 * WLS);
  int* cl = (int*)(pool + 8 * WLS + 32 * 9);
  for (int i = t; i < 2048; i += 256) {           // wr is [c][e]; chunk i covers c=i>>1, e0=(i&1)*4
    f32x4 v = ((const f32x4*)wr)[i];
    int c0 = i >> 1, e0 = (i & 1) << 2;
    wl[(e0 + 0) * WLS + c0] = v[0]; wl[(e0 + 1) * WLS + c0] = v[1];
    wl[(e0 + 2) * WLS + c0] = v[2]; wl[(e0 + 3) * WLS + c0] = v[3];
  }
  if (t < 8) cl[t] = 0;
  __syncthreads();
  int tok0 = b * 32;
  int tl = t >> 3, e = t & 7;
  size_t tok = (size_t)tok0 + tl;
  const f32x4* xr = (const f32x4*)(x + tok * C);
  const f32x4* wv4 = (const f32x4*)&wl[e * WLS];
  float a0 = 0.f, a1 = 0.f, a2 = 0.f, a3 = 0.f;
#pragma unroll 4
  for (int i = 0; i < C / 4; ++i) {
    f32x4 xv = xr[i], wv = wv4[i];
    a0 += xv[0] * wv[0]; a1 += xv[1] * wv[1];
    a2 += xv[2] * wv[2]; a3 += xv[3] * wv[3];
  }
  lg[tl][e] = (a0 + a1) + (a2 + a3);
  __syncthreads();
  if (t < 32) {
    int myTok = tok0 + t;
    float v0 = -1e30f; int i0 = 0;
#pragma unroll
    for (int q = 0; q < 8; ++q) { float v = lg[t][q]; if (v > v0) { v0 = v; i0 = q; } }
    float v1 = -1e30f; int i1 = 0;
#pragma unroll
    for (int q = 0; q < 8; ++q) {
      if (q == i0) continue;
      float v = lg[t][q]; if (v > v1) { v1 = v; i1 = q; }
    }
    float dd = expf(v1 - v0);
    float s = 1.f / (1.f + dd);
    tok_e[myTok * 2 + 0] = i0; tok_e[myTok * 2 + 1] = i1;
    tok_p[myTok * 2 + 0] = s;  tok_p[myTok * 2 + 1] = dd * s;
    atomicAdd(&cl[i0], 1); atomicAdd(&cl[i1], 1);
  }
  __syncthreads();
  if (t < 8 && cl[t] > 0) atomicAdd(&counts[t], cl[t]);
  // convert this block's 32 token rows to bf16 (rows are L1/L2-hot from the logit pass)
  const f32x4* xall = (const f32x4*)(x + (size_t)tok0 * C);
  uint2* xb2 = (uint2*)(xb + (size_t)tok0 * C);
  for (int i = t; i < 32 * C / 4; i += 256) {
    f32x4 v = xall[i];
    uint2 o;
    o.x = (u32)f2bf(v[0]) | ((u32)f2bf(v[1]) << 16);
    o.y = (u32)f2bf(v[2]) | ((u32)f2bf(v[3]) << 16);
    xb2[i] = o;
  }
}

// ---------------- build: per-block local offsets + ballot scatter + inverse map ----------------
__global__ void __launch_bounds__(256) k_build(const int* __restrict__ tok_e,
                                               const int* __restrict__ counts,
                                               int* __restrict__ cnt2,
                                               int* __restrict__ offs,
                                               int* __restrict__ list_tok,
                                               int* __restrict__ inv) {
  int gid = blockIdx.x * 256 + threadIdx.x;
  int offv[9]; int off = 0;
#pragma unroll
  for (int q = 0; q < 8; ++q) { offv[q] = off; off += (counts[q] + (BM - 1)) & ~(BM - 1); }
  offv[8] = off;
  if (blockIdx.x == 0 && threadIdx.x < 9) offs[threadIdx.x] = offv[threadIdx.x];
  int lane = threadIdx.x & 63;
#pragma unroll
  for (int s = 0; s < 2; ++s) {
    int e = tok_e[gid * 2 + s];
    for (int q = 0; q < 8; ++q) {
      unsigned long long mask = __ballot(e == q);
      if (mask == 0ull) continue;
      int leader = __ffsll(mask) - 1;
      int cnt = __popcll(mask);
      int base = 0;
      if (lane == leader) base = atomicAdd(&cnt2[q], cnt);
      base = __shfl(base, leader, 64);
      if (e == q) {
        int pos = offv[q] + base + __popcll(mask & ((1ull << lane) - 1ull));
        list_tok[pos] = gid;
        inv[gid * 2 + s] = pos;
      }
    }
  }
}

// ---------------- grouped GEMM: r11-exact (six named LDS arrays, 3-buffer, counted vmcnt) ----------------
// MODE 0: h[row] = relu^2( xb[clamp(tok(row))] @ w1t[e] )    MODE 1: y[row] = h[row] @ w2t[e]
template <int MODE>
__global__ void __launch_bounds__(256, 3) k_gemm(const u16* __restrict__ A,
                                                 const u16* __restrict__ Bt,
                                                 u16* __restrict__ Hout,
                                                 const int* __restrict__ list_tok,
                                                 const int* __restrict__ offs,
                                                 int Ntok) {
  // six statically-distinct buffers: alias analysis proves stage/read disjoint (r13 lesson)
  __shared__ u16 A0[BM * BK], B0[BN * BK], A1[BM * BK], B1[BN * BK], A2[BM * BK], B2[BN * BK];
  int b = blockIdx.x;
  int nper = gridDim.x >> 3;
  int logical = (b & 7) * nper + (b >> 3);   // XCD-chunked bijective swizzle (grid % 8 == 0)
  int m0 = (logical >> 3) * BM;
  int n0 = (logical & 7) * BN;
  if (m0 >= offs[8]) return;
  int e = 0;
#pragma unroll
  for (int q = 1; q < 8; ++q) e += (m0 >= offs[q]);

  int t = threadIdx.x;
  int l = t & 63, w = t >> 6;                // 4 waves
  int wm = w >> 1, wn = w & 1;               // 64x64 out per wave

  // staging (r8-verified): row = w*32 + j*16 + (l>>2) (j=0..1), chunk c=l&3.
  // LDS dest linear (rule 21); global source pre-swizzled: LDS(row,c)=G(row, c^((row>>1)&3)).
  const u16* ag[2]; const u16* bg[2];
#pragma unroll
  for (int j = 0; j < 2; ++j) {
    int row = w * 32 + j * 16 + (l >> 2);
    int coff = (((l & 3) ^ ((row >> 1) & 3)) << 3);   // u16 units
    if (MODE == 0) {
      int tk = list_tok[m0 + row];
      tk = (tk < 0 || tk >= Ntok) ? 0 : tk;   // pad slots stay poisoned -> clamp (never combined)
      ag[j] = A + (size_t)tk * C + coff;
    } else {
      ag[j] = A + (size_t)(m0 + row) * C + coff;
    }
    bg[j] = Bt + (size_t)e * C * D + (size_t)(n0 + row) * 1024 + coff;
  }
  u16* a0 = &A0[w * 1024]; u16* b0 = &B0[w * 1024];
  u16* a1 = &A1[w * 1024]; u16* b1 = &B1[w * 1024];
  u16* a2 = &A2[w * 1024]; u16* b2 = &B2[w * 1024];

  f32x4 acc[4][4];
#pragma unroll
  for (int m = 0; m < 4; ++m)
#pragma unroll
    for (int n = 0; n < 4; ++n) acc[m][n] = (f32x4){0.f, 0.f, 0.f, 0.f};

  auto STAGE = [&](int k0, u16* al, u16* bl) {   // 4 loads per wave per K-tile
#pragma unroll
    for (int j = 0; j < 2; ++j) {
      gl_lds16(ag[j] + k0, al + j * 512);
      gl_lds16(bg[j] + k0, bl + j * 512);
    }
  };
  auto COMPUTE = [&](const u16* Al, const u16* Bl) {
    s16x8 af[4], bf[4];
    int cr = l >> 4;                            // k-chunk 0..3
#pragma unroll
    for (int m = 0; m < 4; ++m) {
      int row = wm * 64 + m * 16 + (l & 15);
      af[m] = *(const s16x8*)&Al[row * BK + ((cr ^ ((row >> 1) & 3)) << 3)];
    }
#pragma unroll
    for (int n = 0; n < 4; ++n) {
      int row = wn * 64 + n * 16 + (l & 15);
      bf[n] = *(const s16x8*)&Bl[row * BK + ((cr ^ ((row >> 1) & 3)) << 3)];
    }
    __builtin_amdgcn_s_setprio(1);              // T5: favor MFMA waves during cluster
#pragma unroll
    for (int m = 0; m < 4; ++m)
#pragma unroll
      for (int n = 0; n < 4; ++n)
        acc[m][n] = __builtin_amdgcn_mfma_f32_16x16x32_bf16(af[m], bf[n], acc[m][n], 0, 0, 0);
    __builtin_amdgcn_s_setprio(0);
  };

  STAGE(0, a0, b0);                 // 4 loads (tile 0)
  STAGE(BK, a1, b1);                // 4 loads (tile 1) -> 8 outstanding
  // phase(t): STAGE(t+2 -> b[(t+2)%3]); waitvm(8) [keep {t+1,t+2}]; bar; COMPUTE(b[t%3]); bar.
#pragma unroll 1
  for (int tt = 0; tt < 30; tt += 3) {
    STAGE((tt + 2) * BK, a2, b2); waitvm<8>(); bar(); COMPUTE(A0, B0); bar();
    STAGE((tt + 3) * BK, a0, b0); waitvm<8>(); bar(); COMPUTE(A1, B1); bar();
    STAGE((tt + 4) * BK, a1, b1); waitvm<8>(); bar(); COMPUTE(A2, B2); bar();
  }
  // last trip (tt=27) staged tiles 29->buf2, 30->buf0, 31->buf1 and computed 27,28,29.
  waitvm<4>(); bar(); COMPUTE(A0, B0);          // tile 30 (buf0); {31} stays in flight
  waitvm<0>(); bar(); COMPUTE(A1, B1);          // tile 31 (buf1)

#pragma unroll
  for (int m = 0; m < 4; ++m) {
#pragma unroll
    for (int r = 0; r < 4; ++r) {
      int grow = m0 + wm * 64 + m * 16 + ((l >> 4) << 2) + r;
      u16* hp = Hout + (size_t)grow * 1024 + n0 + wn * 64 + (l & 15);
#pragma unroll
      for (int n = 0; n < 4; ++n) {
        float v = acc[m][n][r];
        if (MODE == 0) { v = fmaxf(v, 0.f); v = v * v; }
        hp[n * 16] = f2bf(v);
      }
    }
  }
}

// ---------------- combine: out[tok] = p0*y[slot0] + p1*y[slot1] ----------------
__global__ void __launch_bounds__(256) k_combine(const u16* __restrict__ Y,
                                                 const int* __restrict__ inv,
                                                 const float* __restrict__ tok_p,
                                                 float* __restrict__ out) {
  int gid = blockIdx.x * 4 + (threadIdx.x >> 6);   // one wave per token
  int l = threadIdx.x & 63;
  int s0 = inv[gid * 2 + 0], s1 = inv[gid * 2 + 1];
  float p0 = tok_p[gid * 2 + 0], p1 = tok_p[gid * 2 + 1];
  const uint4* y0 = (const uint4*)(Y + (size_t)s0 * 1024);
  const uint4* y1 = (const uint4*)(Y + (size_t)s1 * 1024);
  f32x4* o = (f32x4*)(out + (size_t)gid * 1024);
#pragma unroll
  for (int i = 0; i < 2; ++i) {
    int c = i * 64 + l;
    uint4 a = y0[c], bb = y1[c];
    f32x4 r0, r1;
    r0[0] = p0 * bf2f(a.x & 0xffffu) + p1 * bf2f(bb.x & 0xffffu);
    r0[1] = p0 * bf2f(a.x >> 16)     + p1 * bf2f(bb.x >> 16);
    r0[2] = p0 * bf2f(a.y & 0xffffu) + p1 * bf2f(bb.y & 0xffffu);
    r0[3] = p0 * bf2f(a.y >> 16)     + p1 * bf2f(bb.y >> 16);
    r1[0] = p0 * bf2f(a.z & 0xffffu) + p1 * bf2f(bb.z & 0xffffu);
    r1[1] = p0 * bf2f(a.z >> 16)     + p1 * bf2f(bb.z >> 16);
    r1[2] = p0 * bf2f(a.w & 0xffffu) + p1 * bf2f(bb.w & 0xffffu);
    r1[3] = p0 * bf2f(a.w >> 16)     + p1 * bf2f(bb.w >> 16);
    o[c * 2 + 0] = r0;
    o[c * 2 + 1] = r1;
  }
}

// ---------------- host ----------------
extern "C" void kernel_launch(void* const* d_in, const int* in_sizes, int n_in,
                              void* d_out, int out_size, void* d_ws, size_t ws_size,
                              hipStream_t stream) {
  const float* x  = (const float*)d_in[0];
  const float* wr = (const float*)d_in[1];
  const float* w1 = (const float*)d_in[2];
  const float* w2 = (const float*)d_in[3];
  float* out = (float*)d_out;
  const int Ntok = in_sizes[0] / C;           // 8192
  const int ROWS = 2 * Ntok + E * BM;         // 17408 (max padded grouped rows)
  const int G = (ROWS / BM) * 8;              // 1088 GEMM blocks (== 0 mod 8)
  const int RB = Ntok / 32;                   // 256 router blocks

  char* p = (char*)d_ws;
  u16* xb  = (u16*)p; p += (size_t)Ntok * C * 2;
  u16* w1t = (u16*)p; p += (size_t)E * C * D * 2;
  u16* w2t = (u16*)p; p += (size_t)E * C * D * 2;
  u16* h   = (u16*)p; p += (size_t)ROWS * D * 2;
  u16* y   = (u16*)p; p += (size_t)ROWS * C * 2;
  int* list_tok = (int*)p; p += (size_t)ROWS * 4;
  int* inv = (int*)p; p += (size_t)Ntok * 2 * 4;
  int* tok_e = (int*)p; p += (size_t)Ntok * 2 * 4;
  float* tok_p = (float*)p; p += (size_t)Ntok * 2 * 4;
  int* ints = (int*)p; p += 256;
  int* counts = ints;          // [0..7]
  int* offs = ints + 16;       // [0..8]
  int* cnt2 = ints + 32;       // [0..7]
  (void)ws_size; (void)n_in; (void)out_size;

  hipMemsetAsync(ints, 0, 256, stream);       // zero counters (stream op, capture-safe)
  k_prep<<<RB + 4096, 256, 0, stream>>>(x, wr, w1, w2, xb, w1t, w2t, tok_e, tok_p, counts, RB);
  k_build<<<Ntok / 256, 256, 0, stream>>>(tok_e, counts, cnt2, offs, list_tok, inv);
  k_gemm<0><<<G, 256, 0, stream>>>(xb, w1t, h, list_tok, offs, Ntok);
  k_gemm<1><<<G, 256, 0, stream>>>(h, w2t, y, list_tok, offs, Ntok);
  k_combine<<<Ntok / 4, 256, 0, stream>>>(y, inv, tok_p, out);
}

// Round 17
// 170.473 us; speedup vs baseline: 1.0680x; 1.0680x over previous
//
#include <hip/hip_runtime.h>
#include <stdint.h>

typedef unsigned short u16;
typedef unsigned int u32;

constexpr int C = 1024;
constexpr int E = 8;
constexpr int D = 1024;
constexpr int BM = 128, BN = 128, BK = 32;   // r11 GEMM structure (best measured)
constexpr int WLS = 1032;                    // wl row stride (16B-aligned, bank-staggered)

typedef short s16x8 __attribute__((ext_vector_type(8)));
typedef float f32x4 __attribute__((ext_vector_type(4)));

__device__ __forceinline__ u16 f2bf(float f) {
  union { float f; u32 u; } v; v.f = f;
  return (u16)((v.u + 0x7FFFu + ((v.u >> 16) & 1u)) >> 16);
}
__device__ __forceinline__ float bf2f(u32 u) {
  union { u32 u; float f; } v; v.u = u << 16; return v.f;
}

typedef __attribute__((address_space(1))) const u32 gu32;
typedef __attribute__((address_space(3))) u32 lu32;
__device__ __forceinline__ void gl_lds16(const void* g, void* l) {
  __builtin_amdgcn_global_load_lds((gu32*)g, (lu32*)l, 16, 0, 0);
}
template <int N>
__device__ __forceinline__ void waitvm() {
  asm volatile("s_waitcnt vmcnt(%0)" :: "i"(N) : "memory");
  __builtin_amdgcn_sched_barrier(0);
}
__device__ __forceinline__ void bar() {
  __builtin_amdgcn_s_barrier();
  __builtin_amdgcn_sched_barrier(0);
}

// ---------------- fused prep: router (RB blocks) + w1t/w2t transpose (4096 blocks) ----------------
// Router: 4 waves x 8 rows each, full-row coalesced x reads (1KB/instr), fused x->bf16,
// per-lane 8-expert partials, shfl_xor butterfly reduce. Transpose branch unchanged.
__global__ void __launch_bounds__(256) k_prep(const float* __restrict__ x,
                                              const float* __restrict__ wr,
                                              const float* __restrict__ w1,
                                              const float* __restrict__ w2,
                                              u16* __restrict__ xb,
                                              u16* __restrict__ w1t,
                                              u16* __restrict__ w2t,
                                              int* __restrict__ tok_e,
                                              float* __restrict__ tok_p,
                                              int* __restrict__ counts,
                                              int RB) {
  __shared__ __align__(16) float pool[8 * WLS + 32];   // 33 KB
  int b = blockIdx.x;
  int t = threadIdx.x;
  if (b >= RB) {
    // ---- weight transpose-convert block: w[e][k][n] f32 -> wt[e][n][k] bf16 ----
    float (*tile)[65] = (float (*)[65])pool;           // 16.6 KB of the pool
    int b2 = b - RB;
    int which = b2 >> 11;            // 0: w1, 1: w2
    int rem = b2 & 2047;
    int e = rem >> 8, kt = (rem >> 4) & 15, nt = rem & 15;
    const float* src = (which ? w2 : w1) + (size_t)e * C * D;
    u16* dst = (which ? w2t : w1t) + (size_t)e * C * D;
#pragma unroll
    for (int i = 0; i < 4; ++i) {
      int lin = i * 256 + t;
      int r = lin >> 4, c4 = lin & 15;
      f32x4 v = *(const f32x4*)(src + (size_t)(kt * 64 + r) * 1024 + nt * 64 + c4 * 4);
      tile[r][c4 * 4 + 0] = v[0]; tile[r][c4 * 4 + 1] = v[1];
      tile[r][c4 * 4 + 2] = v[2]; tile[r][c4 * 4 + 3] = v[3];
    }
    __syncthreads();
#pragma unroll
    for (int i = 0; i < 2; ++i) {
      int lin = i * 256 + t;
      int nr = lin >> 3, k8 = lin & 7;
      u32 o[4];
#pragma unroll
      for (int j = 0; j < 4; ++j)
        o[j] = (u32)f2bf(tile[k8 * 8 + 2 * j][nr]) |
               ((u32)f2bf(tile[k8 * 8 + 2 * j + 1][nr]) << 16);
      *(uint4*)(dst + (size_t)(nt * 64 + nr) * 1024 + kt * 64 + k8 * 8) = *(const uint4*)o;
    }
    return;
  }
  // ---- router block: 32 tokens, one full row per wave-pass (4 waves x 8 rows) ----
  float* wl = pool;                               // [8][WLS]
  int* cl = (int*)(pool + 8 * WLS);
  for (int i = t; i < 2048; i += 256) {           // wr is [c][e]; chunk i covers c=i>>1, e0=(i&1)*4
    f32x4 v = ((const f32x4*)wr)[i];
    int c0 = i >> 1, e0 = (i & 1) << 2;
    wl[(e0 + 0) * WLS + c0] = v[0]; wl[(e0 + 1) * WLS + c0] = v[1];
    wl[(e0 + 2) * WLS + c0] = v[2]; wl[(e0 + 3) * WLS + c0] = v[3];
  }
  if (t < 8) cl[t] = 0;
  __syncthreads();
  int tok0 = b * 32;
  int l = t & 63, w = t >> 6;                     // 4 waves; each handles 8 rows
#pragma unroll 1
  for (int rr = 0; rr < 8; ++rr) {
    int row = tok0 + w * 8 + rr;                  // FIX: 4 waves x 8 rows = all 32 tokens
    const f32x4* xr = (const f32x4*)(x + (size_t)row * C);
    uint2* xb2 = (uint2*)(xb + (size_t)row * C);
    float acc[8];
#pragma unroll
    for (int e = 0; e < 8; ++e) acc[e] = 0.f;
#pragma unroll
    for (int it = 0; it < 4; ++it) {
      int c4 = it * 64 + l;                       // f32x4 index; lane-contiguous -> 1KB/instr
      f32x4 xv = xr[c4];
      uint2 o;
      o.x = (u32)f2bf(xv[0]) | ((u32)f2bf(xv[1]) << 16);
      o.y = (u32)f2bf(xv[2]) | ((u32)f2bf(xv[3]) << 16);
      xb2[c4] = o;                                // fused x->bf16 (x read once)
#pragma unroll
      for (int e = 0; e < 8; ++e) {
        f32x4 wv = *(const f32x4*)&wl[e * WLS + c4 * 4];
        acc[e] += xv[0] * wv[0] + xv[1] * wv[1] + xv[2] * wv[2] + xv[3] * wv[3];
      }
    }
    // butterfly reduce across the wave: every lane ends with the full row-dot per expert
#pragma unroll
    for (int off = 1; off < 64; off <<= 1)
#pragma unroll
      for (int e = 0; e < 8; ++e) acc[e] += __shfl_xor(acc[e], off, 64);
    if (l == 0) {
      float v0 = -1e30f; int i0 = 0;
#pragma unroll
      for (int q = 0; q < 8; ++q) { if (acc[q] > v0) { v0 = acc[q]; i0 = q; } }
      float v1 = -1e30f; int i1 = 0;
#pragma unroll
      for (int q = 0; q < 8; ++q) {
        if (q == i0) continue;
        if (acc[q] > v1) { v1 = acc[q]; i1 = q; }
      }
      float dd = expf(v1 - v0);
      float s = 1.f / (1.f + dd);
      tok_e[row * 2 + 0] = i0; tok_e[row * 2 + 1] = i1;
      tok_p[row * 2 + 0] = s;  tok_p[row * 2 + 1] = dd * s;
      atomicAdd(&cl[i0], 1); atomicAdd(&cl[i1], 1);
    }
  }
  __syncthreads();
  if (t < 8 && cl[t] > 0) atomicAdd(&counts[t], cl[t]);
}

// ---------------- build: per-block local offsets + ballot scatter + inverse map ----------------
__global__ void __launch_bounds__(256) k_build(const int* __restrict__ tok_e,
                                               const int* __restrict__ counts,
                                               int* __restrict__ cnt2,
                                               int* __restrict__ offs,
                                               int* __restrict__ list_tok,
                                               int* __restrict__ inv) {
  int gid = blockIdx.x * 256 + threadIdx.x;
  int offv[9]; int off = 0;
#pragma unroll
  for (int q = 0; q < 8; ++q) { offv[q] = off; off += (counts[q] + (BM - 1)) & ~(BM - 1); }
  offv[8] = off;
  if (blockIdx.x == 0 && threadIdx.x < 9) offs[threadIdx.x] = offv[threadIdx.x];
  int lane = threadIdx.x & 63;
#pragma unroll
  for (int s = 0; s < 2; ++s) {
    int e = tok_e[gid * 2 + s];
    for (int q = 0; q < 8; ++q) {
      unsigned long long mask = __ballot(e == q);
      if (mask == 0ull) continue;
      int leader = __ffsll(mask) - 1;
      int cnt = __popcll(mask);
      int base = 0;
      if (lane == leader) base = atomicAdd(&cnt2[q], cnt);
      base = __shfl(base, leader, 64);
      if (e == q) {
        int pos = offv[q] + base + __popcll(mask & ((1ull << lane) - 1ull));
        list_tok[pos] = gid;
        inv[gid * 2 + s] = pos;
      }
    }
  }
}

// ---------------- grouped GEMM: r11-exact (six named LDS arrays, 3-buffer, counted vmcnt) ----------------
// MODE 0: h[row] = relu^2( xb[clamp(tok(row))] @ w1t[e] )    MODE 1: y[row] = h[row] @ w2t[e]
template <int MODE>
__global__ void __launch_bounds__(256, 3) k_gemm(const u16* __restrict__ A,
                                                 const u16* __restrict__ Bt,
                                                 u16* __restrict__ Hout,
                                                 const int* __restrict__ list_tok,
                                                 const int* __restrict__ offs,
                                                 int Ntok) {
  // six statically-distinct buffers: alias analysis proves stage/read disjoint (r13 lesson)
  __shared__ u16 A0[BM * BK], B0[BN * BK], A1[BM * BK], B1[BN * BK], A2[BM * BK], B2[BN * BK];
  int b = blockIdx.x;
  int nper = gridDim.x >> 3;
  int logical = (b & 7) * nper + (b >> 3);   // XCD-chunked bijective swizzle (grid % 8 == 0)
  int m0 = (logical >> 3) * BM;
  int n0 = (logical & 7) * BN;
  if (m0 >= offs[8]) return;
  int e = 0;
#pragma unroll
  for (int q = 1; q < 8; ++q) e += (m0 >= offs[q]);

  int t = threadIdx.x;
  int l = t & 63, w = t >> 6;                // 4 waves
  int wm = w >> 1, wn = w & 1;               // 64x64 out per wave

  // staging (r8-verified): row = w*32 + j*16 + (l>>2) (j=0..1), chunk c=l&3.
  // LDS dest linear (rule 21); global source pre-swizzled: LDS(row,c)=G(row, c^((row>>1)&3)).
  const u16* ag[2]; const u16* bg[2];
#pragma unroll
  for (int j = 0; j < 2; ++j) {
    int row = w * 32 + j * 16 + (l >> 2);
    int coff = (((l & 3) ^ ((row >> 1) & 3)) << 3);   // u16 units
    if (MODE == 0) {
      int tk = list_tok[m0 + row];
      tk = (tk < 0 || tk >= Ntok) ? 0 : tk;   // pad slots stay poisoned -> clamp (never combined)
      ag[j] = A + (size_t)tk * C + coff;
    } else {
      ag[j] = A + (size_t)(m0 + row) * C + coff;
    }
    bg[j] = Bt + (size_t)e * C * D + (size_t)(n0 + row) * 1024 + coff;
  }
  u16* a0 = &A0[w * 1024]; u16* b0 = &B0[w * 1024];
  u16* a1 = &A1[w * 1024]; u16* b1 = &B1[w * 1024];
  u16* a2 = &A2[w * 1024]; u16* b2 = &B2[w * 1024];

  f32x4 acc[4][4];
#pragma unroll
  for (int m = 0; m < 4; ++m)
#pragma unroll
    for (int n = 0; n < 4; ++n) acc[m][n] = (f32x4){0.f, 0.f, 0.f, 0.f};

  auto STAGE = [&](int k0, u16* al, u16* bl) {   // 4 loads per wave per K-tile
#pragma unroll
    for (int j = 0; j < 2; ++j) {
      gl_lds16(ag[j] + k0, al + j * 512);
      gl_lds16(bg[j] + k0, bl + j * 512);
    }
  };
  auto COMPUTE = [&](const u16* Al, const u16* Bl) {
    s16x8 af[4], bf[4];
    int cr = l >> 4;                            // k-chunk 0..3
#pragma unroll
    for (int m = 0; m < 4; ++m) {
      int row = wm * 64 + m * 16 + (l & 15);
      af[m] = *(const s16x8*)&Al[row * BK + ((cr ^ ((row >> 1) & 3)) << 3)];
    }
#pragma unroll
    for (int n = 0; n < 4; ++n) {
      int row = wn * 64 + n * 16 + (l & 15);
      bf[n] = *(const s16x8*)&Bl[row * BK + ((cr ^ ((row >> 1) & 3)) << 3)];
    }
    __builtin_amdgcn_s_setprio(1);              // T5: favor MFMA waves during cluster
#pragma unroll
    for (int m = 0; m < 4; ++m)
#pragma unroll
      for (int n = 0; n < 4; ++n)
        acc[m][n] = __builtin_amdgcn_mfma_f32_16x16x32_bf16(af[m], bf[n], acc[m][n], 0, 0, 0);
    __builtin_amdgcn_s_setprio(0);
  };

  STAGE(0, a0, b0);                 // 4 loads (tile 0)
  STAGE(BK, a1, b1);                // 4 loads (tile 1) -> 8 outstanding
  // phase(t): STAGE(t+2 -> b[(t+2)%3]); waitvm(8) [keep {t+1,t+2}]; bar; COMPUTE(b[t%3]); bar.
#pragma unroll 1
  for (int tt = 0; tt < 30; tt += 3) {
    STAGE((tt + 2) * BK, a2, b2); waitvm<8>(); bar(); COMPUTE(A0, B0); bar();
    STAGE((tt + 3) * BK, a0, b0); waitvm<8>(); bar(); COMPUTE(A1, B1); bar();
    STAGE((tt + 4) * BK, a1, b1); waitvm<8>(); bar(); COMPUTE(A2, B2); bar();
  }
  // last trip (tt=27) staged tiles 29->buf2, 30->buf0, 31->buf1 and computed 27,28,29.
  waitvm<4>(); bar(); COMPUTE(A0, B0);          // tile 30 (buf0); {31} stays in flight
  waitvm<0>(); bar(); COMPUTE(A1, B1);          // tile 31 (buf1)

#pragma unroll
  for (int m = 0; m < 4; ++m) {
#pragma unroll
    for (int r = 0; r < 4; ++r) {
      int grow = m0 + wm * 64 + m * 16 + ((l >> 4) << 2) + r;
      u16* hp = Hout + (size_t)grow * 1024 + n0 + wn * 64 + (l & 15);
#pragma unroll
      for (int n = 0; n < 4; ++n) {
        float v = acc[m][n][r];
        if (MODE == 0) { v = fmaxf(v, 0.f); v = v * v; }
        hp[n * 16] = f2bf(v);
      }
    }
  }
}

// ---------------- combine: out[tok] = p0*y[slot0] + p1*y[slot1] ----------------
__global__ void __launch_bounds__(256) k_combine(const u16* __restrict__ Y,
                                                 const int* __restrict__ inv,
                                                 const float* __restrict__ tok_p,
                                                 float* __restrict__ out) {
  int gid = blockIdx.x * 4 + (threadIdx.x >> 6);   // one wave per token
  int l = threadIdx.x & 63;
  int s0 = inv[gid * 2 + 0], s1 = inv[gid * 2 + 1];
  float p0 = tok_p[gid * 2 + 0], p1 = tok_p[gid * 2 + 1];
  const uint4* y0 = (const uint4*)(Y + (size_t)s0 * 1024);
  const uint4* y1 = (const uint4*)(Y + (size_t)s1 * 1024);
  f32x4* o = (f32x4*)(out + (size_t)gid * 1024);
#pragma unroll
  for (int i = 0; i < 2; ++i) {
    int c = i * 64 + l;
    uint4 a = y0[c], bb = y1[c];
    f32x4 r0, r1;
    r0[0] = p0 * bf2f(a.x & 0xffffu) + p1 * bf2f(bb.x & 0xffffu);
    r0[1] = p0 * bf2f(a.x >> 16)     + p1 * bf2f(bb.x >> 16);
    r0[2] = p0 * bf2f(a.y & 0xffffu) + p1 * bf2f(bb.y & 0xffffu);
    r0[3] = p0 * bf2f(a.y >> 16)     + p1 * bf2f(bb.y >> 16);
    r1[0] = p0 * bf2f(a.z & 0xffffu) + p1 * bf2f(bb.z & 0xffffu);
    r1[1] = p0 * bf2f(a.z >> 16)     + p1 * bf2f(bb.z >> 16);
    r1[2] = p0 * bf2f(a.w & 0xffffu) + p1 * bf2f(bb.w & 0xffffu);
    r1[3] = p0 * bf2f(a.w >> 16)     + p1 * bf2f(bb.w >> 16);
    o[c * 2 + 0] = r0;
    o[c * 2 + 1] = r1;
  }
}

// ---------------- host ----------------
extern "C" void kernel_launch(void* const* d_in, const int* in_sizes, int n_in,
                              void* d_out, int out_size, void* d_ws, size_t ws_size,
                              hipStream_t stream) {
  const float* x  = (const float*)d_in[0];
  const float* wr = (const float*)d_in[1];
  const float* w1 = (const float*)d_in[2];
  const float* w2 = (const float*)d_in[3];
  float* out = (float*)d_out;
  const int Ntok = in_sizes[0] / C;           // 8192
  const int ROWS = 2 * Ntok + E * BM;         // 17408 (max padded grouped rows)
  const int G = (ROWS / BM) * 8;              // 1088 GEMM blocks (== 0 mod 8)
  const int RB = Ntok / 32;                   // 256 router blocks

  char* p = (char*)d_ws;
  u16* xb  = (u16*)p; p += (size_t)Ntok * C * 2;
  u16* w1t = (u16*)p; p += (size_t)E * C * D * 2;
  u16* w2t = (u16*)p; p += (size_t)E * C * D * 2;
  u16* h   = (u16*)p; p += (size_t)ROWS * D * 2;
  u16* y   = (u16*)p; p += (size_t)ROWS * C * 2;
  int* list_tok = (int*)p; p += (size_t)ROWS * 4;
  int* inv = (int*)p; p += (size_t)Ntok * 2 * 4;
  int* tok_e = (int*)p; p += (size_t)Ntok * 2 * 4;
  float* tok_p = (float*)p; p += (size_t)Ntok * 2 * 4;
  int* ints = (int*)p; p += 256;
  int* counts = ints;          // [0..7]
  int* offs = ints + 16;       // [0..8]
  int* cnt2 = ints + 32;       // [0..7]
  (void)ws_size; (void)n_in; (void)out_size;

  hipMemsetAsync(ints, 0, 256, stream);       // zero counters (stream op, capture-safe)
  k_prep<<<RB + 4096, 256, 0, stream>>>(x, wr, w1, w2, xb, w1t, w2t, tok_e, tok_p, counts, RB);
  k_build<<<Ntok / 256, 256, 0, stream>>>(tok_e, counts, cnt2, offs, list_tok, inv);
  k_gemm<0><<<G, 256, 0, stream>>>(xb, w1t, h, list_tok, offs, Ntok);
  k_gemm<1><<<G, 256, 0, stream>>>(h, w2t, y, list_tok, offs, Ntok);
  k_combine<<<Ntok / 4, 256, 0, stream>>>(y, inv, tok_p, out);
}